// Round 1
// baseline (104.355 us; speedup 1.0000x reference)
//
#include <hip/hip_runtime.h>

// ForgetMult (QRNN): xi (8,128,64,32,32) f32.
//   f = sigmoid(xi[:, :64]); x = xi[:, 64:]
//   h_t = f_t * x_t + (1 - f_t) * h_{t-1}  (scan over axis 2, T=64)
// Output (8,64,64,32,32) f32.
//
// Independent sequences: 8 * 64 * 32 * 32 = 524288. One thread handles 4
// adjacent spatial elements (float4, 16B/lane coalesced). Block = 256 threads
// = one (b,c) spatial slice (1024 floats). Grid = 8*64 = 512 blocks.

#define T_STEPS 64
#define SP4 256   // 32*32 / 4 float4 per (b,c,t) slice

__global__ __launch_bounds__(256)
void forgetmult_kernel(const float4* __restrict__ xi, float4* __restrict__ out) {
    const int blk = blockIdx.x;            // b*64 + c
    const int b   = blk >> 6;
    const int c   = blk & 63;
    const int s   = threadIdx.x;           // 0..255 float4-index within slice

    // xi strides (in float4 units): channel stride = 64*256, batch stride = 128*64*256
    const size_t fbase = ((size_t)(b * 128 + c) * T_STEPS) * SP4 + s;
    const size_t xbase = ((size_t)(b * 128 + 64 + c) * T_STEPS) * SP4 + s;
    const size_t obase = ((size_t)(b * 64 + c) * T_STEPS) * SP4 + s;

    float4 h = make_float4(0.f, 0.f, 0.f, 0.f);

    #pragma unroll 4
    for (int t = 0; t < T_STEPS; ++t) {
        const float4 fr = xi[fbase + (size_t)t * SP4];
        const float4 xr = xi[xbase + (size_t)t * SP4];

        const float f0 = 1.0f / (1.0f + __expf(-fr.x));
        const float f1 = 1.0f / (1.0f + __expf(-fr.y));
        const float f2 = 1.0f / (1.0f + __expf(-fr.z));
        const float f3 = 1.0f / (1.0f + __expf(-fr.w));

        // h = f*x + (1-f)*h  ==  h + f*(x - h)
        h.x = fmaf(f0, xr.x - h.x, h.x);
        h.y = fmaf(f1, xr.y - h.y, h.y);
        h.z = fmaf(f2, xr.z - h.z, h.z);
        h.w = fmaf(f3, xr.w - h.w, h.w);

        out[obase + (size_t)t * SP4] = h;
    }
}

extern "C" void kernel_launch(void* const* d_in, const int* in_sizes, int n_in,
                              void* d_out, int out_size, void* d_ws, size_t ws_size,
                              hipStream_t stream) {
    const float4* xi = (const float4*)d_in[0];
    float4* out = (float4*)d_out;
    // 8 batches * 64 channels = 512 blocks, 256 threads each
    forgetmult_kernel<<<dim3(512), dim3(256), 0, stream>>>(xi, out);
}

// Round 3
// 74.035 us; speedup vs baseline: 1.4095x; 1.4095x over previous
//
#include <hip/hip_runtime.h>

// ForgetMult (QRNN): xi (8,128,64,32,32) f32.
//   f = sigmoid(xi[:, :64]); x = xi[:, 64:]
//   h_t = f_t * x_t + (1 - f_t) * h_{t-1}  (scan over axis 2, T=64)
// Output (8,64,64,32,32) f32.
//
// R3: same as R2 but with clang ext_vector_type float2 so the
// nontemporal builtins compile. 262144 threads -> 1024 blocks ->
// 16 waves/CU to hide ~900-cyc HBM latency. Unroll 8, nontemporal
// loads/stores (streaming, zero reuse), approx-rcp sigmoid.

#define T_STEPS 64
#define SP2 512   // float2 per (b,c,t) spatial slice (32*32/2)

typedef float v2f __attribute__((ext_vector_type(2)));

__global__ __launch_bounds__(256)
void forgetmult_kernel(const v2f* __restrict__ xi, v2f* __restrict__ out) {
    const int blk  = blockIdx.x;          // ((b*64)+c)*2 + half
    const int b    = blk >> 7;
    const int rem  = blk & 127;
    const int c    = rem >> 1;
    const int half = rem & 1;
    const int s    = half * 256 + threadIdx.x;   // 0..511 float2-index in slice

    const size_t fbase = ((size_t)(b * 128 + c) * T_STEPS) * SP2 + s;
    const size_t xbase = ((size_t)(b * 128 + 64 + c) * T_STEPS) * SP2 + s;
    const size_t obase = ((size_t)(b * 64 + c) * T_STEPS) * SP2 + s;

    v2f h = {0.f, 0.f};

    #pragma unroll 8
    for (int t = 0; t < T_STEPS; ++t) {
        const v2f fr = __builtin_nontemporal_load(&xi[fbase + (size_t)t * SP2]);
        const v2f xr = __builtin_nontemporal_load(&xi[xbase + (size_t)t * SP2]);

        // sigmoid via fast exp + approx rcp (absmax threshold 9.2e-2 >> rcp err)
        const float f0 = __builtin_amdgcn_rcpf(1.0f + __expf(-fr.x));
        const float f1 = __builtin_amdgcn_rcpf(1.0f + __expf(-fr.y));

        // h = f*x + (1-f)*h  ==  h + f*(x - h)
        h.x = fmaf(f0, xr.x - h.x, h.x);
        h.y = fmaf(f1, xr.y - h.y, h.y);

        __builtin_nontemporal_store(h, &out[obase + (size_t)t * SP2]);
    }
}

extern "C" void kernel_launch(void* const* d_in, const int* in_sizes, int n_in,
                              void* d_out, int out_size, void* d_ws, size_t ws_size,
                              hipStream_t stream) {
    const v2f* xi = (const v2f*)d_in[0];
    v2f* out = (v2f*)d_out;
    // 8 b * 64 c * 2 halves = 1024 blocks, 256 threads each
    forgetmult_kernel<<<dim3(1024), dim3(256), 0, stream>>>(xi, out);
}